// Round 5
// baseline (39.405 us; speedup 1.0000x reference)
//
#include <hip/hip_runtime.h>
#include <math.h>

#define NT 256
#define L_LEN 720
#define NROWS (64 * 321)   // 20544, divisible by 4

#define LOG2E 1.4426950408889634f
#define LN2   0.6931471805599453f

__global__ __launch_bounds__(NT, 8) void trend_kernel(
    const float* __restrict__ x,
    const float* __restrict__ cw0, const float* __restrict__ cb0,
    const float* __restrict__ cw1, const float* __restrict__ cb1,
    const float* __restrict__ cw2, const float* __restrict__ cb2,
    const float* __restrict__ cw3, const float* __restrict__ cb3,
    const float* __restrict__ W1, const float* __restrict__ b1,
    const float* __restrict__ W2, const float* __restrict__ b2,
    float* __restrict__ out)
{
    // one wave per row; 4 independent waves per block; no LDS, no barriers.
    // Key idea: conv outputs are NEVER kept live. Pass 1 fuses conv->exp->
    // (S, Tu) accumulation; pass 2 recomputes the weighted output as a single
    // merged 9-tap conv over the register-held window xw. Live set ~45 VGPRs
    // -> 8 waves/SIMD.
    const int lane = threadIdx.x & 63;
    const int wid  = threadIdx.x >> 6;
    const int row  = blockIdx.x * 4 + wid;

    const float* __restrict__ xr = x + (size_t)row * L_LEN;

    // conv weights: uniform scalar loads -> SGPRs (t >= k folds to 0.0f)
    const float* cws[4] = {cw0, cw1, cw2, cw3};
    const float* cbs[4] = {cb0, cb1, cb2, cb3};
    float w[4][9], bias[4];
#pragma unroll
    for (int s = 0; s < 4; ++s) {
        const int k = 3 + 2 * s;
        bias[s] = cbs[s][0];
#pragma unroll
        for (int t = 0; t < 9; ++t) w[s][t] = (t < k) ? cws[s][t] : 0.0f;
    }

    // lane t owns elements 12t .. 12t+11 ; lanes 60..63 idle (60*12 == 720)
    const bool active = lane < 60;

    float xw[20];           // x[12*lane-4 .. 12*lane+15], stays live to the end
    float S[4]  = {0.f, 0.f, 0.f, 0.f};   // sum 2^u   (= sum e^f)
    float Tu[4] = {0.f, 0.f, 0.f, 0.f};   // sum u*2^u (T = ln2 * Tu)

    if (active) {
        const int e0 = 12 * lane - 4;
#pragma unroll
        for (int q = 0; q < 5; ++q) {
            int e = e0 + 4 * q;
            e = (e < 0) ? 0 : ((e > L_LEN - 4) ? (L_LEN - 4) : e);  // 16B-aligned
            float4 v = *(const float4*)(xr + e);
            xw[4 * q + 0] = v.x; xw[4 * q + 1] = v.y;
            xw[4 * q + 2] = v.z; xw[4 * q + 3] = v.w;
        }
        if (lane == 0)  { xw[0] = 0.f; xw[1] = 0.f; xw[2] = 0.f; xw[3] = 0.f; }
        if (lane == 59) { xw[16] = 0.f; xw[17] = 0.f; xw[18] = 0.f; xw[19] = 0.f; }

        // fused pass: conv -> u = f*log2e -> 2^u -> accumulate S, Tu.
        // u is consumed immediately; nothing stays live per element.
#pragma unroll
        for (int e = 0; e < 12; ++e) {
#pragma unroll
            for (int s = 0; s < 4; ++s) {
                const int k = 3 + 2 * s;
                const int off = 3 - s;          // 4 - k/2
                float acc = bias[s];
#pragma unroll
                for (int u = 0; u < k; ++u)
                    acc = fmaf(w[s][u], xw[e + off + u], acc);
                float uu = acc * LOG2E;
                float ev = __builtin_amdgcn_exp2f(uu);   // v_exp_f32
                S[s]  += ev;
                Tu[s]  = fmaf(uu, ev, Tu[s]);
            }
        }
    }

    // wave-wide reduce of S, Tu (8 values, 6 butterfly levels)
#pragma unroll
    for (int s = 0; s < 4; ++s) {
#pragma unroll
        for (int off = 32; off; off >>= 1) {
            S[s]  += __shfl_xor(S[s],  off);
            Tu[s] += __shfl_xor(Tu[s], off);
        }
    }

    // entropy = ln S - T/S = ln2 * (log2 S - Tu/S)
    float ent[4];
#pragma unroll
    for (int s = 0; s < 4; ++s) {
        float r = __builtin_amdgcn_rcpf(S[s]);
        ent[s] = LN2 * (__builtin_amdgcn_logf(S[s]) - Tu[s] * r);  // v_log_f32 = log2
    }

    // MLP: h = relu(ent @ W1 + b1), one hidden unit per lane (mod 32);
    // logits = h @ W2 + b2 via 32-lane shuffle reduce; softmax -> weights
    const int hidx = lane & 31;
    float h = b1[hidx];
#pragma unroll
    for (int s = 0; s < 4; ++s) h = fmaf(ent[s], W1[s * 32 + hidx], h);
    h = fmaxf(h, 0.0f);

    const float4 w2v = ((const float4*)W2)[hidx];
    float lg[4] = {h * w2v.x, h * w2v.y, h * w2v.z, h * w2v.w};
#pragma unroll
    for (int c = 0; c < 4; ++c) {
#pragma unroll
        for (int off = 16; off; off >>= 1)
            lg[c] += __shfl_xor(lg[c], off);
    }
    lg[0] += b2[0]; lg[1] += b2[1]; lg[2] += b2[2]; lg[3] += b2[3];

    float m = fmaxf(fmaxf(lg[0], lg[1]), fmaxf(lg[2], lg[3]));
    float e0w = __expf(lg[0] - m), e1w = __expf(lg[1] - m);
    float e2w = __expf(lg[2] - m), e3w = __expf(lg[3] - m);
    float inv = 1.0f / (e0w + e1w + e2w + e3w);
    const float wgt[4] = {e0w * inv, e1w * inv, e2w * inv, e3w * inv};

    // merge the 4 kernels with the mixing weights: out = Bm + sum_j Wm[j]*xw[e+j]
    float Wm[9] = {0.f, 0.f, 0.f, 0.f, 0.f, 0.f, 0.f, 0.f, 0.f};
    float Bm = 0.f;
#pragma unroll
    for (int s = 0; s < 4; ++s) {
        const int k = 3 + 2 * s;
        const int off = 3 - s;
#pragma unroll
        for (int u = 0; u < k; ++u)
            Wm[off + u] = fmaf(wgt[s], w[s][u], Wm[off + u]);
        Bm = fmaf(wgt[s], bias[s], Bm);
    }

    // output pass: merged 9-tap conv from the register-held window
    if (active) {
        float* __restrict__ orow = out + (size_t)row * L_LEN + 12 * lane;
#pragma unroll
        for (int q = 0; q < 3; ++q) {
            float4 v;
#pragma unroll
            for (int c = 0; c < 4; ++c) {
                const int e = 4 * q + c;
                float acc = Bm;
#pragma unroll
                for (int j = 0; j < 9; ++j)
                    acc = fmaf(Wm[j], xw[e + j], acc);
                ((float*)&v)[c] = acc;
            }
            *(float4*)(orow + 4 * q) = v;
        }
    }
}

extern "C" void kernel_launch(void* const* d_in, const int* in_sizes, int n_in,
                              void* d_out, int out_size, void* d_ws, size_t ws_size,
                              hipStream_t stream) {
    const float* xp  = (const float*)d_in[0];
    const float* cw0 = (const float*)d_in[1];
    const float* cb0 = (const float*)d_in[2];
    const float* cw1 = (const float*)d_in[3];
    const float* cb1 = (const float*)d_in[4];
    const float* cw2 = (const float*)d_in[5];
    const float* cb2 = (const float*)d_in[6];
    const float* cw3 = (const float*)d_in[7];
    const float* cb3 = (const float*)d_in[8];
    const float* W1  = (const float*)d_in[9];
    const float* b1  = (const float*)d_in[10];
    const float* W2  = (const float*)d_in[11];
    const float* b2  = (const float*)d_in[12];
    float* outp = (float*)d_out;

    trend_kernel<<<NROWS / 4, NT, 0, stream>>>(xp, cw0, cb0, cw1, cb1, cw2, cb2,
                                               cw3, cb3, W1, b1, W2, b2, outp);
}

// Round 6
// 39.371 us; speedup vs baseline: 1.0009x; 1.0009x over previous
//
#include <hip/hip_runtime.h>
#include <math.h>

#define NT 256
#define L_LEN 720
#define NROWS (64 * 321)   // 20544, divisible by 8

#define LOG2E 1.4426950408889634f
#define LN2   0.6931471805599453f

__global__ __launch_bounds__(NT, 4) void trend_kernel(
    const float* __restrict__ x,
    const float* __restrict__ cw0, const float* __restrict__ cb0,
    const float* __restrict__ cw1, const float* __restrict__ cb1,
    const float* __restrict__ cw2, const float* __restrict__ cb2,
    const float* __restrict__ cw3, const float* __restrict__ cb3,
    const float* __restrict__ W1, const float* __restrict__ b1,
    const float* __restrict__ W2, const float* __restrict__ b2,
    float* __restrict__ out)
{
    // TWO rows per wave (independent dep chains -> 2x ILP), 4 waves per block,
    // no LDS, no barriers. Windows are pinned in registers immediately after
    // load so the allocator can't remat/re-fetch them (R5's failure mode).
    const int lane = threadIdx.x & 63;
    const int wid  = threadIdx.x >> 6;
    const int pair = blockIdx.x * 4 + wid;          // wave index
    const int rowA = 2 * pair;
    const int rowB = rowA + 1;

    const float* __restrict__ xa = x + (size_t)rowA * L_LEN;
    const float* __restrict__ xb = x + (size_t)rowB * L_LEN;

    // conv weights: uniform scalar loads -> SGPRs
    const float* cws[4] = {cw0, cw1, cw2, cw3};
    const float* cbs[4] = {cb0, cb1, cb2, cb3};
    float w[4][9], bias[4];
#pragma unroll
    for (int s = 0; s < 4; ++s) {
        const int k = 3 + 2 * s;
        bias[s] = cbs[s][0];
#pragma unroll
        for (int t = 0; t < 9; ++t) w[s][t] = (t < k) ? cws[s][t] : 0.0f;
    }

    // lane t owns elements 12t .. 12t+11 of each row; lanes 60..63 idle
    const bool active = lane < 60;

    float xwA[20], xwB[20];
    float SA[4]  = {0.f, 0.f, 0.f, 0.f}, SB[4]  = {0.f, 0.f, 0.f, 0.f};
    float TuA[4] = {0.f, 0.f, 0.f, 0.f}, TuB[4] = {0.f, 0.f, 0.f, 0.f};

    if (active) {
        const int e0 = 12 * lane - 4;
#pragma unroll
        for (int q = 0; q < 5; ++q) {
            int e = e0 + 4 * q;
            e = (e < 0) ? 0 : ((e > L_LEN - 4) ? (L_LEN - 4) : e);  // 16B-aligned
            float4 va = *(const float4*)(xa + e);
            float4 vb = *(const float4*)(xb + e);
            xwA[4 * q + 0] = va.x; xwA[4 * q + 1] = va.y;
            xwA[4 * q + 2] = va.z; xwA[4 * q + 3] = va.w;
            xwB[4 * q + 0] = vb.x; xwB[4 * q + 1] = vb.y;
            xwB[4 * q + 2] = vb.z; xwB[4 * q + 3] = vb.w;
        }
        if (lane == 0) {
#pragma unroll
            for (int t = 0; t < 4; ++t) { xwA[t] = 0.f; xwB[t] = 0.f; }
        }
        if (lane == 59) {
#pragma unroll
            for (int t = 16; t < 20; ++t) { xwA[t] = 0.f; xwB[t] = 0.f; }
        }

        // Pin the windows: loads happen exactly once, stay live to the end.
#pragma unroll
        for (int t = 0; t < 20; ++t) {
            asm volatile("" : "+v"(xwA[t]));
            asm volatile("" : "+v"(xwB[t]));
        }

        // fused pass: conv -> u = f*log2e -> 2^u -> accumulate S, Tu.
        // A and B chains are interleaved at source level for ILP.
#pragma unroll
        for (int e = 0; e < 12; ++e) {
#pragma unroll
            for (int s = 0; s < 4; ++s) {
                const int k = 3 + 2 * s;
                const int off = 3 - s;          // 4 - k/2
                float aA = bias[s], aB = bias[s];
#pragma unroll
                for (int u = 0; u < k; ++u) {
                    aA = fmaf(w[s][u], xwA[e + off + u], aA);
                    aB = fmaf(w[s][u], xwB[e + off + u], aB);
                }
                float uA = aA * LOG2E,  uB = aB * LOG2E;
                float eA = __builtin_amdgcn_exp2f(uA);
                float eB = __builtin_amdgcn_exp2f(uB);
                SA[s] += eA;                    SB[s] += eB;
                TuA[s] = fmaf(uA, eA, TuA[s]);  TuB[s] = fmaf(uB, eB, TuB[s]);
            }
        }
    }

    // wave-wide reduce: 16 independent values -> butterfly latency overlaps
#pragma unroll
    for (int s = 0; s < 4; ++s) {
#pragma unroll
        for (int off = 32; off; off >>= 1) {
            SA[s]  += __shfl_xor(SA[s],  off);
            SB[s]  += __shfl_xor(SB[s],  off);
            TuA[s] += __shfl_xor(TuA[s], off);
            TuB[s] += __shfl_xor(TuB[s], off);
        }
    }

    // entropy = ln2 * (log2 S - Tu/S)   (shift-free form, fp32-safe for f~N(0,1))
    float entA[4], entB[4];
#pragma unroll
    for (int s = 0; s < 4; ++s) {
        entA[s] = LN2 * (__builtin_amdgcn_logf(SA[s])
                         - TuA[s] * __builtin_amdgcn_rcpf(SA[s]));
        entB[s] = LN2 * (__builtin_amdgcn_logf(SB[s])
                         - TuB[s] * __builtin_amdgcn_rcpf(SB[s]));
    }

    // MLP for both rows: h = relu(ent @ W1 + b1) one hidden unit per lane
    // (mod 32); logits via 32-lane shuffle reduce; softmax -> mixing weights
    const int hidx = lane & 31;
    float hA = b1[hidx], hB = hA;
#pragma unroll
    for (int s = 0; s < 4; ++s) {
        const float w1v = W1[s * 32 + hidx];
        hA = fmaf(entA[s], w1v, hA);
        hB = fmaf(entB[s], w1v, hB);
    }
    hA = fmaxf(hA, 0.0f); hB = fmaxf(hB, 0.0f);

    const float4 w2v = ((const float4*)W2)[hidx];
    float lgA[4] = {hA * w2v.x, hA * w2v.y, hA * w2v.z, hA * w2v.w};
    float lgB[4] = {hB * w2v.x, hB * w2v.y, hB * w2v.z, hB * w2v.w};
#pragma unroll
    for (int c = 0; c < 4; ++c) {
#pragma unroll
        for (int off = 16; off; off >>= 1) {
            lgA[c] += __shfl_xor(lgA[c], off);
            lgB[c] += __shfl_xor(lgB[c], off);
        }
    }
#pragma unroll
    for (int c = 0; c < 4; ++c) { lgA[c] += b2[c]; lgB[c] += b2[c]; }

    float mA = fmaxf(fmaxf(lgA[0], lgA[1]), fmaxf(lgA[2], lgA[3]));
    float mB = fmaxf(fmaxf(lgB[0], lgB[1]), fmaxf(lgB[2], lgB[3]));
    float eA0 = __expf(lgA[0] - mA), eA1 = __expf(lgA[1] - mA);
    float eA2 = __expf(lgA[2] - mA), eA3 = __expf(lgA[3] - mA);
    float eB0 = __expf(lgB[0] - mB), eB1 = __expf(lgB[1] - mB);
    float eB2 = __expf(lgB[2] - mB), eB3 = __expf(lgB[3] - mB);
    float invA = 1.0f / (eA0 + eA1 + eA2 + eA3);
    float invB = 1.0f / (eB0 + eB1 + eB2 + eB3);
    const float wgtA[4] = {eA0 * invA, eA1 * invA, eA2 * invA, eA3 * invA};
    const float wgtB[4] = {eB0 * invB, eB1 * invB, eB2 * invB, eB3 * invB};

    // merge the 4 kernels per row: out = Bm + sum_j Wm[j] * xw[e+j]
    float WmA[9] = {0,0,0,0,0,0,0,0,0}, WmB[9] = {0,0,0,0,0,0,0,0,0};
    float BmA = 0.f, BmB = 0.f;
#pragma unroll
    for (int s = 0; s < 4; ++s) {
        const int k = 3 + 2 * s;
        const int off = 3 - s;
#pragma unroll
        for (int u = 0; u < k; ++u) {
            WmA[off + u] = fmaf(wgtA[s], w[s][u], WmA[off + u]);
            WmB[off + u] = fmaf(wgtB[s], w[s][u], WmB[off + u]);
        }
        BmA = fmaf(wgtA[s], bias[s], BmA);
        BmB = fmaf(wgtB[s], bias[s], BmB);
    }

    // output: merged 9-tap conv from the pinned windows, float4 stores
    if (active) {
        float* __restrict__ oa = out + (size_t)rowA * L_LEN + 12 * lane;
        float* __restrict__ ob = out + (size_t)rowB * L_LEN + 12 * lane;
#pragma unroll
        for (int q = 0; q < 3; ++q) {
            float4 va, vb;
#pragma unroll
            for (int c = 0; c < 4; ++c) {
                const int e = 4 * q + c;
                float accA = BmA, accB = BmB;
#pragma unroll
                for (int j = 0; j < 9; ++j) {
                    accA = fmaf(WmA[j], xwA[e + j], accA);
                    accB = fmaf(WmB[j], xwB[e + j], accB);
                }
                ((float*)&va)[c] = accA;
                ((float*)&vb)[c] = accB;
            }
            *(float4*)(oa + 4 * q) = va;
            *(float4*)(ob + 4 * q) = vb;
        }
    }
}

extern "C" void kernel_launch(void* const* d_in, const int* in_sizes, int n_in,
                              void* d_out, int out_size, void* d_ws, size_t ws_size,
                              hipStream_t stream) {
    const float* xp  = (const float*)d_in[0];
    const float* cw0 = (const float*)d_in[1];
    const float* cb0 = (const float*)d_in[2];
    const float* cw1 = (const float*)d_in[3];
    const float* cb1 = (const float*)d_in[4];
    const float* cw2 = (const float*)d_in[5];
    const float* cb2 = (const float*)d_in[6];
    const float* cw3 = (const float*)d_in[7];
    const float* cb3 = (const float*)d_in[8];
    const float* W1  = (const float*)d_in[9];
    const float* b1  = (const float*)d_in[10];
    const float* W2  = (const float*)d_in[11];
    const float* b2  = (const float*)d_in[12];
    float* outp = (float*)d_out;

    trend_kernel<<<NROWS / 8, NT, 0, stream>>>(xp, cw0, cb0, cw1, cb1, cw2, cb2,
                                               cw3, cb3, W1, b1, W2, b2, outp);
}